// Round 3
// baseline (15684.940 us; speedup 1.0000x reference)
//
#include <hip/hip_runtime.h>
#include <hip/hip_fp16.h>

#define B_  16
#define T_  400
#define F_  512
#define U_  1024
#define G4_ 4096
#define NBLK 256

typedef __attribute__((ext_vector_type(8))) short short8;
typedef __attribute__((ext_vector_type(4))) float f32x4;

__device__ __forceinline__ unsigned bf16bits(float f) {
  unsigned u = __float_as_uint(f);
  return (u + 0x7fffu + ((u >> 16) & 1u)) >> 16;   // RNE f32->bf16
}
__device__ __forceinline__ float sigm(float x)   { return 1.f/(1.f + __expf(-x)); }
__device__ __forceinline__ float tanh_f(float x) { return 2.f/(1.f + __expf(-2.f*x)) - 1.f; }

// ---------------- Phase 1: xw[dir] = x @ k_dir + b_dir (f16 out) ---------
__global__ __launch_bounds__(256) void gemm_xw(
    const float* __restrict__ X,
    const float* __restrict__ Kf, const float* __restrict__ Kb,
    const float* __restrict__ Bf, const float* __restrict__ Bb,
    __half* __restrict__ xwf, __half* __restrict__ xwb)
{
  const int dir = blockIdx.z;
  const float* Km   = dir ? Kb : Kf;
  const float* bias = dir ? Bb : Bf;
  __half* outp      = dir ? xwb : xwf;
  const int m0 = blockIdx.x * 64;
  const int n0 = blockIdx.y * 64;
  const int tid = threadIdx.x;
  const int tx = tid & 15, ty = tid >> 4;

  __shared__ float As[32][68];
  __shared__ float Bs[32][68];

  float acc[4][4] = {};

  for (int k0 = 0; k0 < F_; k0 += 32) {
    #pragma unroll
    for (int i = 0; i < 8; ++i) {
      int flat = i*256 + tid;
      int kk = flat & 31, m = flat >> 5;
      As[kk][m] = X[(size_t)(m0+m)*F_ + k0 + kk];
    }
    #pragma unroll
    for (int i = 0; i < 8; ++i) {
      int flat = i*256 + tid;
      int n = flat & 63, kk = flat >> 6;
      Bs[kk][n] = Km[(size_t)(k0+kk)*G4_ + n0 + n];
    }
    __syncthreads();
    #pragma unroll
    for (int kk = 0; kk < 32; ++kk) {
      float4 av = *reinterpret_cast<const float4*>(&As[kk][ty*4]);
      float4 bv = *reinterpret_cast<const float4*>(&Bs[kk][tx*4]);
      float a[4] = {av.x, av.y, av.z, av.w};
      float b[4] = {bv.x, bv.y, bv.z, bv.w};
      #pragma unroll
      for (int i = 0; i < 4; ++i)
        #pragma unroll
        for (int j = 0; j < 4; ++j)
          acc[i][j] += a[i]*b[j];
    }
    __syncthreads();
  }
  #pragma unroll
  for (int i = 0; i < 4; ++i) {
    int m = m0 + ty*4 + i;
    #pragma unroll
    for (int j = 0; j < 4; ++j) {
      int n = n0 + tx*4 + j;
      outp[(size_t)m*G4_ + n] = __float2half_rn(acc[i][j] + bias[n]);
    }
  }
}

// ---------------- Phase 2: persistent bidirectional LSTM (MFMA) ----------
// 256 WGs x 256 threads; WG -> (dir = wg>>7, u0 = (wg&127)*8), 32 gate-cols.
// LDS: h_bf [16 b][1024+16] bf16; r_bf [32 c][1024+16] bf16 (transposed);
// z_s [4 waves][16][33] f32 partials. Wave w contracts K range [w*256,+256).
// Sync: per-WG monotonic flag; consumers spin on own-dir 128 flags.
__global__ __launch_bounds__(256, 1) void lstm_rec(
    const __half* __restrict__ xwf, const __half* __restrict__ xwb,
    const float* __restrict__ Rf, const float* __restrict__ Rb,
    const float* __restrict__ gammav, const float* __restrict__ betav,
    const float* __restrict__ mmean, const float* __restrict__ mvar,
    unsigned short* __restrict__ hbb,   // [par2][dir2][16][1024] bf16 bits
    float* __restrict__ outp,           // [16][400][2048] f32
    unsigned* __restrict__ flags)       // [256] monotonic
{
  __shared__ unsigned short h_bf[16*1040];   // 33280 B
  __shared__ unsigned short r_bf[32*1040];   // 66560 B
  __shared__ float z_s[4*528];               //  8448 B

  const int wg  = blockIdx.x;
  const int dir = wg >> 7;
  const int u0  = (wg & 127) * 8;
  const __half* xw = dir ? xwb : xwf;
  const float*  R  = dir ? Rb  : Rf;
  const int tid  = threadIdx.x;
  const int wid  = tid >> 6;
  const int lane = tid & 63;

  // ---- stage recurrent weights transposed: r_bf[c][k] = bf16(R[k][gc(c)]) ----
  {
    const int c4 = (tid & 7) * 4;                       // cols c4..c4+3 (same gate)
    const int kb = (tid >> 3) * 32;                     // 32 k's
    const int gcol = ((c4 >> 3) * U_) + u0 + (c4 & 7);
    for (int kk = 0; kk < 32; ++kk) {
      const float4 rv = *reinterpret_cast<const float4*>(&R[(size_t)(kb+kk)*G4_ + gcol]);
      r_bf[(c4+0)*1040 + kb+kk] = (unsigned short)bf16bits(rv.x);
      r_bf[(c4+1)*1040 + kb+kk] = (unsigned short)bf16bits(rv.y);
      r_bf[(c4+2)*1040 + kb+kk] = (unsigned short)bf16bits(rv.z);
      r_bf[(c4+3)*1040 + kb+kk] = (unsigned short)bf16bits(rv.w);
    }
  }

  float inv = 0.f, add = 0.f, cst = 0.f;
  const int gb = tid >> 3, uu = tid & 7;   // reduce-thread mapping (tid<128)
  if (tid < 128) {
    const int j = dir*U_ + u0 + uu;
    inv = gammav[j] * rsqrtf(mvar[j] + 1e-3f);
    add = betav[j] - mmean[j]*inv;
    hbb[(size_t)((0*2 + dir)*16 + gb)*U_ + u0 + uu] = 0;   // h parity-0 init
  }
  __threadfence();
  __syncthreads();
  if (tid == 0)
    __hip_atomic_store(&flags[wg], 1u, __ATOMIC_RELEASE, __HIP_MEMORY_SCOPE_AGENT);

  // MFMA fragment addressing (per lane)
  const int arow = lane & 15;              // A row = batch, B col = gate-col
  const int kgrp = lane >> 4;              // k-octet group
  const int kbase0 = wid*256 + kgrp*8;
  const unsigned short* hrow = &h_bf[arow*1040];
  const unsigned short* bc0  = &r_bf[arow*1040];          // tile 0: cols 0..15
  const unsigned short* bc1  = &r_bf[(16 + arow)*1040];   // tile 1: cols 16..31

  for (int s = 0; s < T_; ++s) {
    const int tin = dir ? (T_-1-s) : s;

    // xw prefetch for this step (before spin -> latency hidden)
    float xv0=0.f, xv1=0.f, xv2=0.f, xv3=0.f;
    if (tid < 128) {
      const __half* xp = &xw[((size_t)gb*T_ + tin)*G4_ + u0 + uu];
      xv0 = __half2float(xp[0]);    xv1 = __half2float(xp[1024]);
      xv2 = __half2float(xp[2048]); xv3 = __half2float(xp[3072]);
    }

    // wait for h(s): own-dir producers posted s+1
    if (tid < 128) {
      const unsigned tgt = (unsigned)(s + 1);
      while (__hip_atomic_load(&flags[dir*128 + tid], __ATOMIC_RELAXED,
                               __HIP_MEMORY_SCOPE_AGENT) < tgt)
        __builtin_amdgcn_s_sleep(1);
    }
    __threadfence();
    __syncthreads();

    // stage h: 32 KB global bf16 -> LDS (verbatim, padded rows)
    {
      const unsigned short* hg = &hbb[(size_t)((s&1)*2 + dir)*16*U_];
      #pragma unroll
      for (int i = 0; i < 8; ++i) {
        const int c = i*256 + tid;               // 16B-chunk id
        const int row = c >> 7, within = c & 127;
        const uint4 v = *reinterpret_cast<const uint4*>(&hg[(size_t)row*U_ + within*8]);
        *reinterpret_cast<uint4*>(&h_bf[row*1040 + within*8]) = v;
      }
    }
    __syncthreads();

    // compute: 8 k-steps x 2 col-tiles, K-range per wave = 256
    f32x4 acc0 = {0.f,0.f,0.f,0.f}, acc1 = {0.f,0.f,0.f,0.f};
    #pragma unroll
    for (int ks = 0; ks < 8; ++ks) {
      const int kb = kbase0 + ks*32;
      const short8 a   = *reinterpret_cast<const short8*>(&hrow[kb]);
      const short8 b0v = *reinterpret_cast<const short8*>(&bc0[kb]);
      const short8 b1v = *reinterpret_cast<const short8*>(&bc1[kb]);
      acc0 = __builtin_amdgcn_mfma_f32_16x16x32_bf16(a, b0v, acc0, 0, 0, 0);
      acc1 = __builtin_amdgcn_mfma_f32_16x16x32_bf16(a, b1v, acc1, 0, 0, 0);
    }
    // z partials: C/D layout col=lane&15, row=(lane>>4)*4+reg  [m89-verified]
    {
      const int col = lane & 15, rbase = (lane >> 4)*4;
      float* zw = &z_s[wid*528];
      #pragma unroll
      for (int r = 0; r < 4; ++r) {
        zw[(rbase+r)*33 + col]      = acc0[r];
        zw[(rbase+r)*33 + 16 + col] = acc1[r];
      }
    }
    __syncthreads();

    // reduce 4 wave-partials + gates + state update (tid<128)
    if (tid < 128) {
      float zi = xv0, zf = xv1, zg = xv2, zo = xv3;
      #pragma unroll
      for (int w = 0; w < 4; ++w) {
        const float* zr = &z_s[w*528 + gb*33];
        zi += zr[uu]; zf += zr[8+uu]; zg += zr[16+uu]; zo += zr[24+uu];
      }
      const float ig = sigm(zi), fg = sigm(zf), og = sigm(zo);
      const float gg = tanh_f(zg);
      cst = fg*cst + ig*gg;
      const float hv = og * tanh_f(cst);
      hbb[(size_t)((((s+1)&1)*2 + dir)*16 + gb)*U_ + u0 + uu] = (unsigned short)bf16bits(hv);
      outp[((size_t)gb*T_ + tin)*2048 + dir*U_ + u0 + uu] = hv*inv + add;
      __threadfence();
    }
    __syncthreads();
    if (tid == 0)
      __hip_atomic_store(&flags[wg], (unsigned)(s + 2), __ATOMIC_RELEASE,
                         __HIP_MEMORY_SCOPE_AGENT);
  }
}

extern "C" void kernel_launch(void* const* d_in, const int* in_sizes, int n_in,
                              void* d_out, int out_size, void* d_ws, size_t ws_size,
                              hipStream_t stream)
{
  const float* x  = (const float*)d_in[0];
  const float* kf = (const float*)d_in[1];
  const float* rf = (const float*)d_in[2];
  const float* bf = (const float*)d_in[3];
  const float* kb = (const float*)d_in[4];
  const float* rb = (const float*)d_in[5];
  const float* bb = (const float*)d_in[6];
  const float* ga = (const float*)d_in[7];
  const float* be = (const float*)d_in[8];
  const float* mm = (const float*)d_in[9];
  const float* mv = (const float*)d_in[10];
  float* outp = (float*)d_out;

  // ws: [flags 4KB][hbb bf16 2par*2dir*16*1024 = 128KB][xwf f16][xwb f16]
  unsigned* flags     = (unsigned*)d_ws;
  unsigned short* hbb = (unsigned short*)((char*)d_ws + 4096);
  __half* xwf         = (__half*)((char*)d_ws + 4096 + 131072);
  __half* xwb         = xwf + (size_t)6400*G4_;

  hipMemsetAsync(flags, 0, 4096, stream);
  gemm_xw<<<dim3(100, 64, 2), dim3(256), 0, stream>>>(x, kf, kb, bf, bb, xwf, xwb);
  lstm_rec<<<dim3(NBLK), dim3(256), 0, stream>>>(xwf, xwb, rf, rb, ga, be, mm, mv,
                                                 hbb, outp, flags);
}

// Round 4
// 3287.366 us; speedup vs baseline: 4.7713x; 4.7713x over previous
//
#include <hip/hip_runtime.h>
#include <hip/hip_fp16.h>

#define B_  16
#define T_  400
#define F_  512
#define U_  1024
#define G4_ 4096
#define NBLK 256

typedef __attribute__((ext_vector_type(8))) short short8;
typedef __attribute__((ext_vector_type(4))) float f32x4;

__device__ __forceinline__ unsigned bf16bits(float f) {
  unsigned u = __float_as_uint(f);
  return (u + 0x7fffu + ((u >> 16) & 1u)) >> 16;   // RNE f32->bf16
}
__device__ __forceinline__ float sigm(float x)   { return 1.f/(1.f + __expf(-x)); }
__device__ __forceinline__ float tanh_f(float x) { return 2.f/(1.f + __expf(-2.f*x)) - 1.f; }

// relaxed agent-scope atomics: sc1 accesses go to the coherence point,
// no L2 writeback/invalidate needed (the round-3 killer was __threadfence).
__device__ __forceinline__ unsigned ald(const unsigned* p) {
  return __hip_atomic_load(p, __ATOMIC_RELAXED, __HIP_MEMORY_SCOPE_AGENT);
}
__device__ __forceinline__ void ast(unsigned* p, unsigned v) {
  __hip_atomic_store(p, v, __ATOMIC_RELAXED, __HIP_MEMORY_SCOPE_AGENT);
}
// hand-rolled release store: per-wave vmcnt(0) then sc1 store — NO buffer_wbl2.
__device__ __forceinline__ void release_store(unsigned* p, unsigned v) {
  asm volatile("s_waitcnt vmcnt(0)\n\t"
               "global_store_dword %0, %1, off sc0 sc1"
               :: "v"(p), "v"(v) : "memory");
}

// ---------------- Phase 1: xw[dir] = x @ k_dir + b_dir (f16 out) ---------
__global__ __launch_bounds__(256) void gemm_xw(
    const float* __restrict__ X,
    const float* __restrict__ Kf, const float* __restrict__ Kb,
    const float* __restrict__ Bf, const float* __restrict__ Bb,
    __half* __restrict__ xwf, __half* __restrict__ xwb)
{
  const int dir = blockIdx.z;
  const float* Km   = dir ? Kb : Kf;
  const float* bias = dir ? Bb : Bf;
  __half* outp      = dir ? xwb : xwf;
  const int m0 = blockIdx.x * 64;
  const int n0 = blockIdx.y * 64;
  const int tid = threadIdx.x;
  const int tx = tid & 15, ty = tid >> 4;

  __shared__ float As[32][68];
  __shared__ float Bs[32][68];

  float acc[4][4] = {};

  for (int k0 = 0; k0 < F_; k0 += 32) {
    #pragma unroll
    for (int i = 0; i < 8; ++i) {
      int flat = i*256 + tid;
      int kk = flat & 31, m = flat >> 5;
      As[kk][m] = X[(size_t)(m0+m)*F_ + k0 + kk];
    }
    #pragma unroll
    for (int i = 0; i < 8; ++i) {
      int flat = i*256 + tid;
      int n = flat & 63, kk = flat >> 6;
      Bs[kk][n] = Km[(size_t)(k0+kk)*G4_ + n0 + n];
    }
    __syncthreads();
    #pragma unroll
    for (int kk = 0; kk < 32; ++kk) {
      float4 av = *reinterpret_cast<const float4*>(&As[kk][ty*4]);
      float4 bv = *reinterpret_cast<const float4*>(&Bs[kk][tx*4]);
      float a[4] = {av.x, av.y, av.z, av.w};
      float b[4] = {bv.x, bv.y, bv.z, bv.w};
      #pragma unroll
      for (int i = 0; i < 4; ++i)
        #pragma unroll
        for (int j = 0; j < 4; ++j)
          acc[i][j] += a[i]*b[j];
    }
    __syncthreads();
  }
  #pragma unroll
  for (int i = 0; i < 4; ++i) {
    int m = m0 + ty*4 + i;
    #pragma unroll
    for (int j = 0; j < 4; ++j) {
      int n = n0 + tx*4 + j;
      outp[(size_t)m*G4_ + n] = __float2half_rn(acc[i][j] + bias[n]);
    }
  }
}

// ---------------- Phase 2: persistent bidirectional LSTM (MFMA) ----------
// 256 WGs x 256 threads; WG -> (dir = wg>>7, u0 = (wg&127)*8), 32 gate-cols.
// h exchange: global [par][dir][16][1024] bf16 as packed dwords, ALL accesses
// relaxed agent atomics (sc1). Sync: per-WG monotonic flag, release via asm.
// Waves stage only their own K-quarter of h into a private LDS region.
__global__ __launch_bounds__(256, 1) void lstm_rec(
    const __half* __restrict__ xwf, const __half* __restrict__ xwb,
    const float* __restrict__ Rf, const float* __restrict__ Rb,
    const float* __restrict__ gammav, const float* __restrict__ betav,
    const float* __restrict__ mmean, const float* __restrict__ mvar,
    unsigned* __restrict__ hw,      // [par2][dir2][16][512] dwords (bf16 pairs)
    float* __restrict__ outp,       // [16][400][2048] f32
    unsigned* __restrict__ flags)   // [256] monotonic
{
  __shared__ unsigned short r_bf[32*1040];     // 66560 B  [c][k] bf16
  __shared__ unsigned short h_bf[4][16*264];   // 33792 B  per-wave [b][256k +8pad]
  __shared__ float z_s[4*528];                 //  8448 B  [wave][16][33]
  __shared__ unsigned short htmp[128];         //   256 B  h handoff to packer

  const int wg  = blockIdx.x;
  const int dir = wg >> 7;
  const int u0  = (wg & 127) * 8;
  const __half* xw = dir ? xwb : xwf;
  const float*  R  = dir ? Rb  : Rf;
  const int tid  = threadIdx.x;
  const int wid  = tid >> 6;
  const int lane = tid & 63;

  // ---- stage recurrent weights transposed: r_bf[c][k] = bf16(R[k][gc(c)]) ----
  {
    const int c4 = (tid & 7) * 4;
    const int kb = (tid >> 3) * 32;
    const int gcol = ((c4 >> 3) * U_) + u0 + (c4 & 7);
    for (int kk = 0; kk < 32; ++kk) {
      const float4 rv = *reinterpret_cast<const float4*>(&R[(size_t)(kb+kk)*G4_ + gcol]);
      r_bf[(c4+0)*1040 + kb+kk] = (unsigned short)bf16bits(rv.x);
      r_bf[(c4+1)*1040 + kb+kk] = (unsigned short)bf16bits(rv.y);
      r_bf[(c4+2)*1040 + kb+kk] = (unsigned short)bf16bits(rv.z);
      r_bf[(c4+3)*1040 + kb+kk] = (unsigned short)bf16bits(rv.w);
    }
  }

  float inv = 0.f, add = 0.f, cst = 0.f;
  const int gb = tid >> 3, uu = tid & 7;   // reduce-thread mapping (tid<128)
  if (tid < 128) {
    const int j = dir*U_ + u0 + uu;
    inv = gammav[j] * rsqrtf(mvar[j] + 1e-3f);
    add = betav[j] - mmean[j]*inv;
  }
  // h(0)=0 for our slice, parity 0 — wave 0, atomic dword stores
  if (tid < 64) {
    const int b = tid >> 2, up = tid & 3;
    ast(&hw[(size_t)(0*2 + dir)*8192 + b*512 + (u0 >> 1) + up], 0u);
  }
  __syncthreads();                         // r_bf staged
  if (tid == 0) release_store(&flags[wg], 1u);

  // MFMA fragment addressing (per lane); k-offsets are wave-local [0,256)
  const int arow = lane & 15;
  const int kgrp = lane >> 4;
  const unsigned short* ha  = &h_bf[wid][arow*264];
  const unsigned short* bc0 = &r_bf[arow*1040 + wid*256];
  const unsigned short* bc1 = &r_bf[(16 + arow)*1040 + wid*256];
  const unsigned* fb = &flags[dir*128];

  for (int s = 0; s < T_; ++s) {
    const int tin = dir ? (T_-1-s) : s;

    // xw prefetch for this step (read-only, normal loads, issued pre-spin)
    float xv0=0.f, xv1=0.f, xv2=0.f, xv3=0.f;
    if (tid < 128) {
      const __half* xp = &xw[((size_t)gb*T_ + tin)*G4_ + u0 + uu];
      xv0 = __half2float(xp[0]);    xv1 = __half2float(xp[1024]);
      xv2 = __half2float(xp[2048]); xv3 = __half2float(xp[3072]);
    }

    // spin: every wave watches all 128 own-dir flags (2 per lane)
    {
      const unsigned tgt = (unsigned)(s + 1);
      for (;;) {
        const unsigned f0 = ald(&fb[2*lane]);
        const unsigned f1 = ald(&fb[2*lane + 1]);
        if (__all((f0 >= tgt) && (f1 >= tgt))) break;
        __builtin_amdgcn_s_sleep(1);
      }
      asm volatile("" ::: "memory");       // compiler barrier; HW coherent via sc1
    }

    // stage this wave's K-quarter of h: 32 atomic dword loads -> private LDS
    {
      const unsigned* hg = hw + (size_t)((s&1)*2 + dir)*8192 + wid*128;
      unsigned v[32];
      #pragma unroll
      for (int i = 0; i < 32; ++i) {
        const int flat = i*64 + lane;
        v[i] = ald(&hg[(flat >> 7)*512 + (flat & 127)]);
      }
      unsigned* hl = (unsigned*)h_bf[wid];
      #pragma unroll
      for (int i = 0; i < 32; ++i) {
        const int flat = i*64 + lane;
        hl[(flat >> 7)*132 + (flat & 127)] = v[i];
      }
    }

    // compute: 8 k-steps x 2 col-tiles (wave covers global k in [wid*256, +256))
    f32x4 acc0 = {0.f,0.f,0.f,0.f}, acc1 = {0.f,0.f,0.f,0.f};
    #pragma unroll
    for (int ks = 0; ks < 8; ++ks) {
      const int kb = ks*32 + kgrp*8;
      const short8 a   = *reinterpret_cast<const short8*>(&ha[kb]);
      const short8 b0v = *reinterpret_cast<const short8*>(&bc0[kb]);
      const short8 b1v = *reinterpret_cast<const short8*>(&bc1[kb]);
      acc0 = __builtin_amdgcn_mfma_f32_16x16x32_bf16(a, b0v, acc0, 0, 0, 0);
      acc1 = __builtin_amdgcn_mfma_f32_16x16x32_bf16(a, b1v, acc1, 0, 0, 0);
    }
    // z partials: D layout col=lane&15, row=kgrp*4+reg  [round-3 verified]
    {
      const int col = lane & 15, rbase = kgrp*4;
      float* zw = &z_s[wid*528];
      #pragma unroll
      for (int r = 0; r < 4; ++r) {
        zw[(rbase+r)*33 + col]      = acc0[r];
        zw[(rbase+r)*33 + 16 + col] = acc1[r];
      }
    }
    __syncthreads();                       // z partials complete

    // reduce 4 wave-partials + gates + state update (tid<128)
    if (tid < 128) {
      float zi = xv0, zf = xv1, zg = xv2, zo = xv3;
      #pragma unroll
      for (int w = 0; w < 4; ++w) {
        const float* zr = &z_s[w*528 + gb*33];
        zi += zr[uu]; zf += zr[8+uu]; zg += zr[16+uu]; zo += zr[24+uu];
      }
      const float ig = sigm(zi), fg = sigm(zf), og = sigm(zo);
      const float gg = tanh_f(zg);
      cst = fg*cst + ig*gg;
      const float hv = og * tanh_f(cst);
      htmp[tid] = (unsigned short)bf16bits(hv);
      outp[((size_t)gb*T_ + tin)*2048 + dir*U_ + u0 + uu] = hv*inv + add;
    }
    __syncthreads();                       // htmp ready

    // wave 0: pack h pairs -> atomic dword stores -> release own flag
    if (tid < 64) {
      const int b = tid >> 2, up = tid & 3;
      const unsigned lo = htmp[b*8 + up*2];
      const unsigned hi = htmp[b*8 + up*2 + 1];
      ast(&hw[(size_t)(((s+1)&1)*2 + dir)*8192 + b*512 + (u0 >> 1) + up],
          lo | (hi << 16));
    }
    if (tid == 0)
      release_store(&flags[wg], (unsigned)(s + 2));   // vmcnt(0) covers wave-0 stores
  }
}

extern "C" void kernel_launch(void* const* d_in, const int* in_sizes, int n_in,
                              void* d_out, int out_size, void* d_ws, size_t ws_size,
                              hipStream_t stream)
{
  const float* x  = (const float*)d_in[0];
  const float* kf = (const float*)d_in[1];
  const float* rf = (const float*)d_in[2];
  const float* bf = (const float*)d_in[3];
  const float* kb = (const float*)d_in[4];
  const float* rb = (const float*)d_in[5];
  const float* bb = (const float*)d_in[6];
  const float* ga = (const float*)d_in[7];
  const float* be = (const float*)d_in[8];
  const float* mm = (const float*)d_in[9];
  const float* mv = (const float*)d_in[10];
  float* outp = (float*)d_out;

  // ws: [flags 4KB][hw dwords 2par*2dir*16*512*4B = 128KB][xwf f16][xwb f16]
  unsigned* flags = (unsigned*)d_ws;
  unsigned* hw    = (unsigned*)((char*)d_ws + 4096);
  __half* xwf     = (__half*)((char*)d_ws + 4096 + 131072);
  __half* xwb     = xwf + (size_t)6400*G4_;

  hipMemsetAsync(flags, 0, 4096, stream);
  gemm_xw<<<dim3(100, 64, 2), dim3(256), 0, stream>>>(x, kf, kb, bf, bb, xwf, xwb);
  lstm_rec<<<dim3(NBLK), dim3(256), 0, stream>>>(xwf, xwb, rf, rb, ga, be, mm, mv,
                                                 hw, outp, flags);
}

// Round 5
// 2469.256 us; speedup vs baseline: 6.3521x; 1.3313x over previous
//
#include <hip/hip_runtime.h>
#include <hip/hip_fp16.h>

#define B_  16
#define T_  400
#define F_  512
#define U_  1024
#define G4_ 4096
#define NBLK 256

typedef __attribute__((ext_vector_type(8))) short short8;
typedef __attribute__((ext_vector_type(4))) float f32x4;

__device__ __forceinline__ unsigned bf16bits(float f) {
  unsigned u = __float_as_uint(f);
  return (u + 0x7fffu + ((u >> 16) & 1u)) >> 16;   // RNE f32->bf16
}
__device__ __forceinline__ float sigm(float x)   { return 1.f/(1.f + __expf(-x)); }
__device__ __forceinline__ float tanh_f(float x) { return 2.f/(1.f + __expf(-2.f*x)) - 1.f; }

__device__ __forceinline__ unsigned ald(const unsigned* p) {
  return __hip_atomic_load(p, __ATOMIC_RELAXED, __HIP_MEMORY_SCOPE_AGENT);
}
__device__ __forceinline__ void ast(unsigned* p, unsigned v) {
  __hip_atomic_store(p, v, __ATOMIC_RELAXED, __HIP_MEMORY_SCOPE_AGENT);
}
// coherent 16B load (bypass L1/L2 -> coherence point); caller must waitcnt.
__device__ __forceinline__ uint4 ald4(const unsigned* p) {
  uint4 v;
  asm volatile("global_load_dwordx4 %0, %1, off sc0 sc1" : "=v"(v) : "v"(p));
  return v;
}
__device__ __forceinline__ void release_store(unsigned* p, unsigned v) {
  asm volatile("s_waitcnt vmcnt(0)\n\t"
               "global_store_dword %0, %1, off sc0 sc1"
               :: "v"(p), "v"(v) : "memory");
}

// ---------------- Phase 1: xw[dir] = x @ k_dir + b_dir (MFMA bf16) -------
// 64x64 tile / WG of 256 (4 waves as 2x2 of 32x32), K-step 32.
__global__ __launch_bounds__(256) void gemm_xw(
    const float* __restrict__ X,
    const float* __restrict__ Kf, const float* __restrict__ Kb,
    const float* __restrict__ Bf, const float* __restrict__ Bb,
    __half* __restrict__ xwf, __half* __restrict__ xwb)
{
  const int dir = blockIdx.z;
  const float* Km   = dir ? Kb : Kf;
  const float* bias = dir ? Bb : Bf;
  __half* outp      = dir ? xwb : xwf;
  const int m0 = blockIdx.x * 64;
  const int n0 = blockIdx.y * 64;
  const int tid = threadIdx.x, wid = tid >> 6, lane = tid & 63;

  __shared__ unsigned short A_bf[64*40];   // [m][k] row stride 40 halves (80B)
  __shared__ unsigned short B_bf[64*40];   // [n][k]

  const int wm = wid >> 1, wn = wid & 1;
  const int arow = lane & 15, kgrp = lane >> 4;
  const int sm = tid & 63, skoct = tid >> 6;   // staging: row sm, k-octet skoct

  f32x4 acc00 = {0.f,0.f,0.f,0.f}, acc01 = {0.f,0.f,0.f,0.f};
  f32x4 acc10 = {0.f,0.f,0.f,0.f}, acc11 = {0.f,0.f,0.f,0.f};

  for (int k0 = 0; k0 < F_; k0 += 32) {
    // A: x[m0+sm][k0+skoct*8 ..+8] -> bf16
    {
      const float* xp = &X[(size_t)(m0+sm)*F_ + k0 + skoct*8];
      const float4 v0 = *reinterpret_cast<const float4*>(xp);
      const float4 v1 = *reinterpret_cast<const float4*>(xp + 4);
      short8 t;
      t[0]=(short)bf16bits(v0.x); t[1]=(short)bf16bits(v0.y);
      t[2]=(short)bf16bits(v0.z); t[3]=(short)bf16bits(v0.w);
      t[4]=(short)bf16bits(v1.x); t[5]=(short)bf16bits(v1.y);
      t[6]=(short)bf16bits(v1.z); t[7]=(short)bf16bits(v1.w);
      *reinterpret_cast<short8*>(&A_bf[sm*40 + skoct*8]) = t;
    }
    // B: Km[k0+skoct*8+j][n0+sm] -> B_bf[sm][skoct*8+j]
    {
      short8 t;
      #pragma unroll
      for (int j = 0; j < 8; ++j)
        t[j] = (short)bf16bits(Km[(size_t)(k0+skoct*8+j)*G4_ + n0 + sm]);
      *reinterpret_cast<short8*>(&B_bf[sm*40 + skoct*8]) = t;
    }
    __syncthreads();
    const short8 a0 = *reinterpret_cast<const short8*>(&A_bf[(wm*32 + arow)*40      + kgrp*8]);
    const short8 a1 = *reinterpret_cast<const short8*>(&A_bf[(wm*32 + 16 + arow)*40 + kgrp*8]);
    const short8 b0 = *reinterpret_cast<const short8*>(&B_bf[(wn*32 + arow)*40      + kgrp*8]);
    const short8 b1 = *reinterpret_cast<const short8*>(&B_bf[(wn*32 + 16 + arow)*40 + kgrp*8]);
    acc00 = __builtin_amdgcn_mfma_f32_16x16x32_bf16(a0, b0, acc00, 0, 0, 0);
    acc01 = __builtin_amdgcn_mfma_f32_16x16x32_bf16(a0, b1, acc01, 0, 0, 0);
    acc10 = __builtin_amdgcn_mfma_f32_16x16x32_bf16(a1, b0, acc10, 0, 0, 0);
    acc11 = __builtin_amdgcn_mfma_f32_16x16x32_bf16(a1, b1, acc11, 0, 0, 0);
    __syncthreads();
  }
  // epilogue: D row = kgrp*4+r (m), col = arow (n)  [validated mapping]
  #pragma unroll
  for (int tm = 0; tm < 2; ++tm) {
    #pragma unroll
    for (int tn = 0; tn < 2; ++tn) {
      const f32x4 a = tm ? (tn ? acc11 : acc10) : (tn ? acc01 : acc00);
      const int n = n0 + wn*32 + tn*16 + arow;
      const float bv = bias[n];
      #pragma unroll
      for (int r = 0; r < 4; ++r) {
        const int m = m0 + wm*32 + tm*16 + kgrp*4 + r;
        outp[(size_t)m*G4_ + n] = __float2half_rn(a[r] + bv);
      }
    }
  }
}

// ---------------- Phase 2: persistent bidirectional LSTM (MFMA) ----------
// 256 WGs x 256 threads; WG -> (dir = wg>>7, u0 = (wg&127)*8), 32 gate-cols.
// h: global dwords, coherent loads straight into MFMA A-fragments (no LDS).
// Per-wave spin: wave w waits only its 32 K-quarter producers' flags.
__global__ __launch_bounds__(256, 1) void lstm_rec(
    const __half* __restrict__ xwf, const __half* __restrict__ xwb,
    const float* __restrict__ Rf, const float* __restrict__ Rb,
    const float* __restrict__ gammav, const float* __restrict__ betav,
    const float* __restrict__ mmean, const float* __restrict__ mvar,
    unsigned* __restrict__ hw,      // [par2][dir2][16][512] dwords (bf16 pairs)
    float* __restrict__ outp,       // [16][400][2048] f32
    unsigned* __restrict__ flags)   // [256] monotonic
{
  __shared__ unsigned short r_bf[32*1040];     // 66560 B  [c][k] bf16
  __shared__ float z_s[4*528];                 //  8448 B  [wave][16][33]
  __shared__ unsigned char occ_pad[8192];      // force 1 block/CU (>80KB total)

  const int wg  = blockIdx.x;
  const int dir = wg >> 7;
  const int u0  = (wg & 127) * 8;
  const __half* xw = dir ? xwb : xwf;
  const float*  R  = dir ? Rb  : Rf;
  const int tid  = threadIdx.x;
  const int wid  = tid >> 6;
  const int lane = tid & 63;

  if ((unsigned long long)hw == 1ull) occ_pad[tid] = 0;   // defeat DCE, never true

  // stage recurrent weights transposed: r_bf[c][k] = bf16(R[k][gc(c)])
  {
    const int c4 = (tid & 7) * 4;
    const int kb = (tid >> 3) * 32;
    const int gcol = ((c4 >> 3) * U_) + u0 + (c4 & 7);
    for (int kk = 0; kk < 32; ++kk) {
      const float4 rv = *reinterpret_cast<const float4*>(&R[(size_t)(kb+kk)*G4_ + gcol]);
      r_bf[(c4+0)*1040 + kb+kk] = (unsigned short)bf16bits(rv.x);
      r_bf[(c4+1)*1040 + kb+kk] = (unsigned short)bf16bits(rv.y);
      r_bf[(c4+2)*1040 + kb+kk] = (unsigned short)bf16bits(rv.z);
      r_bf[(c4+3)*1040 + kb+kk] = (unsigned short)bf16bits(rv.w);
    }
  }

  float inv = 0.f, add = 0.f, cst = 0.f;
  const int gb = tid >> 3, uu = tid & 7;   // reduce-thread mapping (tid<128)
  if (tid < 128) {
    const int j = dir*U_ + u0 + uu;
    inv = gammav[j] * rsqrtf(mvar[j] + 1e-3f);
    add = betav[j] - mmean[j]*inv;
  }
  if (tid < 64) {                          // h(0)=0, parity 0, wave 0 stores
    const int b = tid >> 2, up = tid & 3;
    ast(&hw[(size_t)(0*2 + dir)*8192 + b*512 + (u0 >> 1) + up], 0u);
  }
  __syncthreads();                         // r_bf staged
  if (tid == 0) release_store(&flags[wg], 1u);   // vmcnt(0) covers wave-0 h stores

  // MFMA fragment addressing
  const int arow = lane & 15;              // A row = batch; B col = gate-col
  const int kgrp = lane >> 4;
  const unsigned short* bc0 = &r_bf[arow*1040 + wid*256];
  const unsigned short* bc1 = &r_bf[(16 + arow)*1040 + wid*256];
  const unsigned* myflag = &flags[dir*128 + wid*32 + (lane & 31)];
  const size_t hfrag_off = (size_t)arow*512 + wid*128 + kgrp*4;

  for (int s = 0; s < T_; ++s) {
    const int tin = dir ? (T_-1-s) : s;

    // xw prefetch (issued pre-spin; latency hidden under the wait)
    float xv0=0.f, xv1=0.f, xv2=0.f, xv3=0.f;
    if (tid < 128) {
      const __half* xp = &xw[((size_t)gb*T_ + tin)*G4_ + u0 + uu];
      xv0 = __half2float(xp[0]);    xv1 = __half2float(xp[1024]);
      xv2 = __half2float(xp[2048]); xv3 = __half2float(xp[3072]);
    }

    // per-wave spin: only this wave's 32 K-quarter producers
    {
      const unsigned tgt = (unsigned)(s + 1);
      for (;;) {
        const unsigned f = ald(myflag);
        if (__all((int)(f >= tgt))) break;
        __builtin_amdgcn_s_sleep(1);
      }
      asm volatile("" ::: "memory");
    }

    // h fragments: coherent 16B loads straight to registers
    const unsigned* hgp = hw + (size_t)((s&1)*2 + dir)*8192 + hfrag_off;
    uint4 av0 = ald4(hgp);        uint4 av1 = ald4(hgp + 16);
    uint4 av2 = ald4(hgp + 32);   uint4 av3 = ald4(hgp + 48);
    uint4 av4 = ald4(hgp + 64);   uint4 av5 = ald4(hgp + 80);
    uint4 av6 = ald4(hgp + 96);   uint4 av7 = ald4(hgp + 112);
    asm volatile("s_waitcnt vmcnt(0)" ::: "memory");
    __builtin_amdgcn_sched_barrier(0);

    f32x4 acc0 = {0.f,0.f,0.f,0.f}, acc1 = {0.f,0.f,0.f,0.f};
    #pragma unroll
    for (int ks = 0; ks < 8; ++ks) {
      uint4 av;
      switch (ks) {  // static selection (keep in registers)
        case 0: av = av0; break; case 1: av = av1; break;
        case 2: av = av2; break; case 3: av = av3; break;
        case 4: av = av4; break; case 5: av = av5; break;
        case 6: av = av6; break; default: av = av7; break;
      }
      const short8 a   = *reinterpret_cast<const short8*>(&av);
      const short8 b0v = *reinterpret_cast<const short8*>(&bc0[ks*32 + kgrp*8]);
      const short8 b1v = *reinterpret_cast<const short8*>(&bc1[ks*32 + kgrp*8]);
      acc0 = __builtin_amdgcn_mfma_f32_16x16x32_bf16(a, b0v, acc0, 0, 0, 0);
      acc1 = __builtin_amdgcn_mfma_f32_16x16x32_bf16(a, b1v, acc1, 0, 0, 0);
    }
    // z partials: D col=lane&15 (gate-col), row=kgrp*4+reg (batch)
    {
      const int col = lane & 15, rbase = kgrp*4;
      float* zw = &z_s[wid*528];
      #pragma unroll
      for (int r = 0; r < 4; ++r) {
        zw[(rbase+r)*33 + col]      = acc0[r];
        zw[(rbase+r)*33 + 16 + col] = acc1[r];
      }
    }
    __syncthreads();                       // z partials complete

    float hv = 0.f;
    if (tid < 128) {
      float zi = xv0, zf = xv1, zg = xv2, zo = xv3;
      #pragma unroll
      for (int w = 0; w < 4; ++w) {
        const float* zr = &z_s[w*528 + gb*33];
        zi += zr[uu]; zf += zr[8+uu]; zg += zr[16+uu]; zo += zr[24+uu];
      }
      const float ig = sigm(zi), fg = sigm(zf), og = sigm(zo);
      const float gg = tanh_f(zg);
      cst = fg*cst + ig*gg;
      hv = og * tanh_f(cst);
      const unsigned hvb = bf16bits(hv);
      const unsigned hnb = (unsigned)__shfl_down((int)hvb, 1);
      if (!(uu & 1))
        ast(&hw[(size_t)((((s+1)&1)*2 + dir)*16 + gb)*512 + (u0 >> 1) + (uu >> 1)],
            hvb | (hnb << 16));
      asm volatile("s_waitcnt vmcnt(0)" ::: "memory");   // h stores complete
    }
    __syncthreads();                       // both producer waves drained
    if (tid == 0)
      release_store(&flags[wg], (unsigned)(s + 2));
    if (tid < 128)                         // off the critical path now
      outp[((size_t)gb*T_ + tin)*2048 + dir*U_ + u0 + uu] = hv*inv + add;
  }
}

extern "C" void kernel_launch(void* const* d_in, const int* in_sizes, int n_in,
                              void* d_out, int out_size, void* d_ws, size_t ws_size,
                              hipStream_t stream)
{
  const float* x  = (const float*)d_in[0];
  const float* kf = (const float*)d_in[1];
  const float* rf = (const float*)d_in[2];
  const float* bf = (const float*)d_in[3];
  const float* kb = (const float*)d_in[4];
  const float* rb = (const float*)d_in[5];
  const float* bb = (const float*)d_in[6];
  const float* ga = (const float*)d_in[7];
  const float* be = (const float*)d_in[8];
  const float* mm = (const float*)d_in[9];
  const float* mv = (const float*)d_in[10];
  float* outp = (float*)d_out;

  // ws: [flags 4KB][hw dwords 2par*2dir*16*512*4B = 128KB][xwf f16][xwb f16]
  unsigned* flags = (unsigned*)d_ws;
  unsigned* hw    = (unsigned*)((char*)d_ws + 4096);
  __half* xwf     = (__half*)((char*)d_ws + 4096 + 131072);
  __half* xwb     = xwf + (size_t)6400*G4_;

  hipMemsetAsync(flags, 0, 4096, stream);
  gemm_xw<<<dim3(100, 64, 2), dim3(256), 0, stream>>>(x, kf, kb, bf, bb, xwf, xwb);
  lstm_rec<<<dim3(NBLK), dim3(256), 0, stream>>>(xwf, xwb, rf, rb, ga, be, mm, mv,
                                                 hw, outp, flags);
}